// Round 3
// baseline (1028.168 us; speedup 1.0000x reference)
//
#include <hip/hip_runtime.h>

// Problem constants (from reference)
constexpr int T = 30;
constexpr int B = 8192;
constexpr int I = 784;        // row = 3136 B = 49 * 64 B (64B-aligned segments)
constexpr int O = 10;
constexpr int ROWS = T * B;   // 245760
constexpr int BO = B * O;     // 81920

constexpr int RPB = 256;      // rows per block (1 thread : 1 row)
constexpr int CHUNK = 16;     // floats per row per LDS chunk (49 chunks)
constexpr int NCH = I / CHUNK;
constexpr int LSTRIDE = 20;   // pad +4: every LDS access 16B-aligned ->
                              // ds_read_b128/ds_write_b128, bank-uniform

// ---------------------------------------------------------------------------
// K0: quantize weights (Q3.12, round-half-even like jnp.round), store as f64
// ---------------------------------------------------------------------------
__global__ __launch_bounds__(256) void k_quant(const float* __restrict__ W,
                                               double* __restrict__ wq) {
    int i = blockIdx.x * 256 + threadIdx.x;
    if (i < O * I) {
        float q = rintf(W[i] * 4096.0f);               // round-half-even, exact *2^12
        q = fminf(fmaxf(q, -32768.0f), 32767.0f);
        wq[i] = (double)(q * 0.000244140625f);         // exact /4096
    }
}

// ---------------------------------------------------------------------------
// K1: skinny GEMM  cur[rid, o] = sum_i x[rid, i] * wq[o, i]
//     Staging: 4-lane groups load contiguous 64B row segments (perfectly
//     coalesced) -> LDS stride-20 (16B-aligned, bank-uniform b128 ops).
//     Compute: thread t owns row t; weights via wave-uniform scalar loads
//     (s_load_dwordx16); f64 accumulation for numerical fidelity.
// ---------------------------------------------------------------------------
__global__ __launch_bounds__(256) void k_gemm(const float* __restrict__ x,
                                              const double* __restrict__ wq,
                                              float* __restrict__ cur) {
    __shared__ float lds[RPB * LSTRIDE];               // 20480 B -> 8 blocks/CU

    const int tid = threadIdx.x;
    const int row0 = blockIdx.x * RPB;

    // load-phase mapping: pass p, thread t -> row p*64 + t/4, float4 slot t%4
    const int lr = tid >> 2;           // 0..63  (row within pass)
    const int lq = tid & 3;            // 0..3   (float4 within 16-float chunk)

    double acc[O];
#pragma unroll
    for (int o = 0; o < O; ++o) acc[o] = 0.0;

#pragma unroll 1
    for (int c = 0; c < NCH; ++c) {
        __syncthreads();               // protect LDS reuse from previous chunk
#pragma unroll
        for (int p = 0; p < 4; ++p) {
            const int r = p * 64 + lr;                 // 0..255
            const float4 v = *reinterpret_cast<const float4*>(
                x + (size_t)(row0 + r) * I + c * CHUNK + lq * 4);
            *reinterpret_cast<float4*>(&lds[r * LSTRIDE + lq * 4]) = v;
        }
        __syncthreads();

        const double* __restrict__ wc = wq + c * CHUNK;
#pragma unroll
        for (int q = 0; q < 4; ++q) {                  // 4 x ds_read_b128
            const float4 xv = *reinterpret_cast<const float4*>(
                &lds[tid * LSTRIDE + q * 4]);
            const double xd0 = (double)xv.x, xd1 = (double)xv.y;
            const double xd2 = (double)xv.z, xd3 = (double)xv.w;
#pragma unroll
            for (int o = 0; o < O; ++o) {              // uniform -> scalar loads
                double s = acc[o];
                s = __fma_rn(xd0, wc[o * I + q * 4 + 0], s);
                s = __fma_rn(xd1, wc[o * I + q * 4 + 1], s);
                s = __fma_rn(xd2, wc[o * I + q * 4 + 2], s);
                s = __fma_rn(xd3, wc[o * I + q * 4 + 3], s);
                acc[o] = s;
            }
        }
    }

    float* __restrict__ op = cur + (size_t)(row0 + tid) * O;
#pragma unroll
    for (int o = 0; o < O; ++o) op[o] = (float)acc[o];
}

// ---------------------------------------------------------------------------
// K2: LIF scan over t.  thread per (b,o) flat index; fully coalesced.
//     snntorch Leaky, reset_mechanism='subtract': reset uses PREVIOUS mem.
// ---------------------------------------------------------------------------
__global__ __launch_bounds__(256) void k_scan(const float* __restrict__ cur,
                                              float* __restrict__ spk,
                                              float* __restrict__ memo) {
    const int j = blockIdx.x * 256 + threadIdx.x;      // 0..BO-1
    float mem = 0.0f;
#pragma unroll
    for (int t = 0; t < T; ++t) {
        const float c = cur[(size_t)t * BO + j];
        const float reset = (mem > 1.0f) ? 1.0f : 0.0f;
        // mem = 0.9375*mem + c - reset   (explicit rn ops: no fma contraction)
        float m = __fmul_rn(0.9375f, mem);
        m = __fadd_rn(m, c);
        m = __fadd_rn(m, -reset);
        mem = m;
        spk[(size_t)t * BO + j]  = (m > 1.0f) ? 1.0f : 0.0f;
        memo[(size_t)t * BO + j] = m;
    }
}

// ---------------------------------------------------------------------------
extern "C" void kernel_launch(void* const* d_in, const int* in_sizes, int n_in,
                              void* d_out, int out_size, void* d_ws, size_t ws_size,
                              hipStream_t stream) {
    const float* x = (const float*)d_in[0];   // [30, 8192, 784] f32
    const float* W = (const float*)d_in[1];   // [10, 784] f32

    double* wq = (double*)d_ws;                          // 7840 f64 = 62720 B
    float* cur = (float*)((char*)d_ws + 65536);          // 2457600 f32
    float* spk  = (float*)d_out;                         // [30,8192,10]
    float* memo = (float*)d_out + (size_t)T * BO;        // [30,8192,10]

    hipLaunchKernelGGL(k_quant, dim3((O * I + 255) / 256), dim3(256), 0, stream, W, wq);
    hipLaunchKernelGGL(k_gemm,  dim3(ROWS / RPB),          dim3(256), 0, stream, x, wq, cur);
    hipLaunchKernelGGL(k_scan,  dim3(BO / 256),            dim3(256), 0, stream, cur, spk, memo);
}